// Round 1
// baseline (267.536 us; speedup 1.0000x reference)
//
#include <hip/hip_runtime.h>
#include <hip/hip_cooperative_groups.h>

namespace cg = cooperative_groups;

// Problem constants (B=4, N=M=8192, D=3)
#define NPTS   8192
#define BATCH  4
#define MSPLIT 16                // m-range splits per (b,dir)
#define QB     4                 // query tiles (32 queries each) per logical wave
#define TILES  (NPTS / 32)       // 256 point-tiles per (cloud,b)
#define TPB    (TILES / MSPLIT)  // 16 db tiles per logical wave
#define ITER   TPB
#define NQTOT  (BATCH * 2 * NPTS)
#define NBLK   1024              // cooperative grid: 4 blocks/CU -> fully resident
#define NPASS  2                 // logical waves per physical wave (8192/4096)

typedef _Float16 f16x8  __attribute__((ext_vector_type(8)));
typedef float    f32x16 __attribute__((ext_vector_type(16)));

// ws layout (bytes):
//   TA  [8 bd][256 tile][64 lane] f16x8   @ 0        (2 MB)  db-role frags
//   QF  [8 bd][256 tile][64 lane] f16x8   @ 2 MB     (2 MB)  query-role frags
//   H   [8 bd][8192] fp32                 @ 4 MB     (256 KB) |p|^2 exact
//   MIN [MSPLIT][8 bd][8192] fp32         @ 4.25 MB  (4 MB)  partial mins
#define TA_OFF  0
#define QF_OFF  (2u << 20)
#define H_OFF   (4u << 20)
#define MIN_OFF ((4u << 20) + (256u << 10))

// min3 tree over the 16 C regs (rows = 16 of 32 db points; other half in lane^32)
__device__ __forceinline__ float red16(const f32x16& d) {
    float a = fminf(fminf(d[0],  d[1]),  d[2]);
    float b = fminf(fminf(d[3],  d[4]),  d[5]);
    float c = fminf(fminf(d[6],  d[7]),  d[8]);
    float e = fminf(fminf(d[9],  d[10]), d[11]);
    float f = fminf(fminf(d[12], d[13]), d[14]);
    float g = fminf(fminf(a, b), d[15]);
    float h = fminf(fminf(c, e), f);
    return fminf(g, h);
}

// Single cooperative kernel: prepack -> grid.sync -> main -> grid.sync -> reduce.
// Eliminates two dependent-dispatch boundaries (~10 us each per rocprof.md).
// Grid fixed at 1024 blocks; __launch_bounds__(256,4) caps VGPR<=128 so
// 4 blocks/CU residency (and thus the cooperative launch) is guaranteed.
__global__ __launch_bounds__(256, 4) void chamfer_fused(
    const float* __restrict__ src, const float* __restrict__ tgt,
    f16x8* __restrict__ TA, f16x8* __restrict__ QF, float* __restrict__ H,
    float* __restrict__ minarr, float* __restrict__ out)
{
    __shared__ float sdata[4];
    const int gtid = blockIdx.x * 256 + (int)threadIdx.x;

    // ---------------- Phase 1: prepack (64K points; blocks 0..255) ----------
    // A (db role)   k = [th.x th.y th.z th.x th.y th.z tl.x tl.y | tl.z tl.x tl.y tl.z hth htl 0 0]
    // B (query role)k = [rh.x rh.y rh.z rl.x rl.y rl.z rh.x rh.y | rh.z rl.x rl.y rl.z  1   1  0 0]
    // (r = -2q). Dot = rh·th + rl·th + rh·tl + rl·tl + hth + htl ≈ ht - 2 q·t.
    if (gtid < NQTOT) {
        if (gtid == 0) out[0] = 0.0f;
        int c = gtid >> 15;
        int r = gtid & 32767;                      // b*8192 + pt
        const float* p = (c ? tgt : src) + (size_t)r * 3;
        float x = p[0], y = p[1], z = p[2];
        float h = x * x + y * y + z * z;
        H[gtid] = h;

        _Float16 thx = (_Float16)x, thy = (_Float16)y, thz = (_Float16)z;
        _Float16 tlx = (_Float16)(x - (float)thx);
        _Float16 tly = (_Float16)(y - (float)thy);
        _Float16 tlz = (_Float16)(z - (float)thz);
        _Float16 hh  = (_Float16)h;
        _Float16 hl  = (_Float16)(h - (float)hh);

        float rx = -2.f * x, ry = -2.f * y, rz = -2.f * z;
        _Float16 rhx = (_Float16)rx, rhy = (_Float16)ry, rhz = (_Float16)rz;
        _Float16 rlx = (_Float16)(rx - (float)rhx);
        _Float16 rly = (_Float16)(ry - (float)rhy);
        _Float16 rlz = (_Float16)(rz - (float)rhz);

        int pt   = r & 8191;
        int bd   = gtid >> 13;                     // c*4+b
        int tile = pt >> 5, ln = pt & 31;
        size_t base = ((size_t)bd * TILES + tile) * 64;

        _Float16 z0 = (_Float16)0.f, one = (_Float16)1.f;
        f16x8 alo = {thx, thy, thz, thx, thy, thz, tlx, tly};
        f16x8 ahi = {tlz, tlx, tly, tlz, hh,  hl,  z0,  z0 };
        TA[base + ln]      = alo;
        TA[base + 32 + ln] = ahi;
        f16x8 blo = {rhx, rhy, rhz, rlx, rly, rlz, rhx, rhy};
        f16x8 bhi = {rhz, rlx, rly, rlz, one, one, z0,  z0 };
        QF[base + ln]      = blo;
        QF[base + 32 + ln] = bhi;
    }
    cg::this_grid().sync();

    // ---------------- Phase 2: main (4096 phys waves x 2 ms-passes) ---------
    {
        const int lane = (int)threadIdx.x & 63;
        const int pw   = gtid >> 6;          // physical wave 0..4095
        const int qw   = pw & 63;
        const int bd   = (pw >> 6) & 7;      // dir*4+b (queries from cloud=dir)
        const int ms0  = pw >> 9;            // 0..7; pass 1 adds +8
        const int bdT  = bd ^ 4;             // db side = opposite cloud

        f16x8 qf[QB];
        size_t qbase = ((size_t)bd * TILES + qw * QB) * 64 + lane;
        #pragma unroll
        for (int t = 0; t < QB; ++t) qf[t] = QF[qbase + t * 64];

        const f32x16 zero = {0.f,0.f,0.f,0.f,0.f,0.f,0.f,0.f,
                             0.f,0.f,0.f,0.f,0.f,0.f,0.f,0.f};

        #pragma unroll 1   // keep register pressure low; passes share qf
        for (int pss = 0; pss < NPASS; ++pss) {
            const int ms = ms0 + pss * 8;
            float mn[QB];
            #pragma unroll
            for (int t = 0; t < QB; ++t) mn[t] = 3.0e38f;

            const size_t tbase = ((size_t)bdT * TILES + ms * TPB) * 64 + lane;

            // Software-pipelined: prefetch next tile while reducing current.
            f16x8 a = TA[tbase];
            for (int i = 0; i < ITER - 1; ++i) {
                f16x8 n = TA[tbase + (size_t)(i + 1) * 64];
                #pragma unroll
                for (int t = 0; t < QB; ++t) {
                    f32x16 d = __builtin_amdgcn_mfma_f32_32x32x16_f16(a, qf[t], zero, 0, 0, 0);
                    mn[t] = fminf(mn[t], red16(d));
                }
                a = n;
            }
            #pragma unroll
            for (int t = 0; t < QB; ++t) {
                f32x16 d = __builtin_amdgcn_mfma_f32_32x32x16_f16(a, qf[t], zero, 0, 0, 0);
                mn[t] = fminf(mn[t], red16(d));
            }

            // Each lane covered 16 of 32 rows per tile; other 16 rows in lane^32.
            #pragma unroll
            for (int t = 0; t < QB; ++t) mn[t] = fminf(mn[t], __shfl_xor(mn[t], 32));

            if (lane < 32) {
                float* basep = minarr + (size_t)ms * NQTOT + (size_t)bd * NPTS
                             + qw * (QB * 32) + lane;
                #pragma unroll
                for (int t = 0; t < QB; ++t) basep[t * 32] = mn[t];
            }
        }
    }
    cg::this_grid().sync();

    // ---------------- Phase 3: reduce (blocks 0..255) -----------------------
    if (gtid < NQTOT) {
        float m = 3.4e38f;
        #pragma unroll
        for (int ms = 0; ms < MSPLIT; ++ms)
            m = fminf(m, minarr[(size_t)ms * NQTOT + gtid]);
        float acc = m + H[gtid];
        #pragma unroll
        for (int off = 32; off > 0; off >>= 1) acc += __shfl_down(acc, off);

        if ((threadIdx.x & 63) == 0) sdata[threadIdx.x >> 6] = acc;
        __syncthreads();
        if (threadIdx.x == 0) {
            float t = (sdata[0] + sdata[1]) + (sdata[2] + sdata[3]);
            atomicAdd(out, t * (1.0f / (float)(BATCH * NPTS)));
        }
    }
}

extern "C" void kernel_launch(void* const* d_in, const int* in_sizes, int n_in,
                              void* d_out, int out_size, void* d_ws, size_t ws_size,
                              hipStream_t stream) {
    const float* src = (const float*)d_in[0];   // (B, N, 3) fp32
    const float* tgt = (const float*)d_in[1];   // (B, M, 3) fp32
    float* out = (float*)d_out;

    f16x8* TA     = (f16x8*)((char*)d_ws + TA_OFF);
    f16x8* QF     = (f16x8*)((char*)d_ws + QF_OFF);
    float* H      = (float*)((char*)d_ws + H_OFF);
    float* minarr = (float*)((char*)d_ws + MIN_OFF);

    void* args[] = {(void*)&src, (void*)&tgt, (void*)&TA, (void*)&QF,
                    (void*)&H, (void*)&minarr, (void*)&out};
    hipLaunchCooperativeKernel((void*)chamfer_fused, dim3(NBLK), dim3(256),
                               args, 0, stream);
}

// Round 2
// 80.221 us; speedup vs baseline: 3.3350x; 3.3350x over previous
//
#include <hip/hip_runtime.h>

// Problem constants (B=4, N=M=8192, D=3)
#define NPTS   8192
#define BATCH  4
#define MSPLIT 16                // m-range splits per (b,dir)
#define QB     4                 // query tiles (32 queries each) per wave
#define TILES  (NPTS / 32)       // 256 point-tiles per (cloud,b)
#define TPB    (TILES / MSPLIT)  // 16 db tiles per wave
#define ITER   TPB               // one tile per inner iteration
#define NQTOT  (BATCH * 2 * NPTS)
#define NWAVES (64 * 8 * MSPLIT) // 8192 logical waves
#define WPB    4                 // waves per workgroup (beat the wg/CU cap)

typedef _Float16 f16x8  __attribute__((ext_vector_type(8)));
typedef float    f32x16 __attribute__((ext_vector_type(16)));

// ws layout (bytes):
//   TA  [8 bd][256 tile][64 lane] f16x8   @ 0        (2 MB)   db-role frags
//   QF  [8 bd][256 tile][64 lane] f16x8   @ 2 MB     (2 MB)   query-role frags
//   H   [8 bd][8192] fp32                 @ 4 MB     (256 KB) |p|^2 exact
//   MIN8[8 bd][8192] uint (monotone enc)  @ 4.25 MB  (256 KB) atomicMin mins
#define TA_OFF  0
#define QF_OFF  (2u << 20)
#define H_OFF   (4u << 20)
#define MIN_OFF ((4u << 20) + (256u << 10))

// ---- Prepack: per point build hi/lo f16 split K-vectors in MFMA lane order.
// A (db role)   k = [th.x th.y th.z  th.x th.y th.z  tl.x tl.y | tl.z tl.x tl.y tl.z  hth htl 0 0]
// B (query role)k = [rh.x rh.y rh.z  rl.x rl.y rl.z  rh.x rh.y | rh.z rl.x rl.y rl.z  1   1   0 0]
// (r = -2q). Dot = rh·th + rl·th + rh·tl + rl·tl + hth + htl ≈ ht - 2 q·t.
// Also inits MIN8 to UINT_MAX (encoded +inf) and zeroes out[0].
__global__ __launch_bounds__(256) void chamfer_prepack(
    const float* __restrict__ src, const float* __restrict__ tgt,
    f16x8* __restrict__ TA, f16x8* __restrict__ QF, float* __restrict__ H,
    unsigned* __restrict__ min8, float* __restrict__ out)
{
    int tid = blockIdx.x * 256 + threadIdx.x;      // (c*4+b)*8192 + pt
    if (tid == 0) out[0] = 0.0f;                   // replaces memset dispatch
    min8[tid] = 0xFFFFFFFFu;                       // init for atomicMin
    int c   = tid >> 15;
    int r   = tid & 32767;                         // b*8192 + pt
    const float* p = (c ? tgt : src) + (size_t)r * 3;
    float x = p[0], y = p[1], z = p[2];
    float h = x * x + y * y + z * z;
    H[tid] = h;

    _Float16 thx = (_Float16)x, thy = (_Float16)y, thz = (_Float16)z;
    _Float16 tlx = (_Float16)(x - (float)thx);
    _Float16 tly = (_Float16)(y - (float)thy);
    _Float16 tlz = (_Float16)(z - (float)thz);
    _Float16 hh  = (_Float16)h;
    _Float16 hl  = (_Float16)(h - (float)hh);

    float rx = -2.f * x, ry = -2.f * y, rz = -2.f * z;
    _Float16 rhx = (_Float16)rx, rhy = (_Float16)ry, rhz = (_Float16)rz;
    _Float16 rlx = (_Float16)(rx - (float)rhx);
    _Float16 rly = (_Float16)(ry - (float)rhy);
    _Float16 rlz = (_Float16)(rz - (float)rhz);

    int pt   = r & 8191;
    int bd   = tid >> 13;                          // c*4+b
    int tile = pt >> 5, ln = pt & 31;
    size_t base = ((size_t)bd * TILES + tile) * 64;

    _Float16 z0 = (_Float16)0.f, one = (_Float16)1.f;
    f16x8 alo = {thx, thy, thz, thx, thy, thz, tlx, tly};
    f16x8 ahi = {tlz, tlx, tly, tlz, hh,  hl,  z0,  z0 };
    TA[base + ln]      = alo;
    TA[base + 32 + ln] = ahi;
    f16x8 blo = {rhx, rhy, rhz, rlx, rly, rlz, rhx, rhy};
    f16x8 bhi = {rhz, rlx, rly, rlz, one, one, z0,  z0 };
    QF[base + ln]      = blo;
    QF[base + 32 + ln] = bhi;
}

// min3 tree over the 16 C regs (rows = 16 of 32 db points; other half in lane^32)
__device__ __forceinline__ float red16(const f32x16& d) {
    float a = fminf(fminf(d[0],  d[1]),  d[2]);
    float b = fminf(fminf(d[3],  d[4]),  d[5]);
    float c = fminf(fminf(d[6],  d[7]),  d[8]);
    float e = fminf(fminf(d[9],  d[10]), d[11]);
    float f = fminf(fminf(d[12], d[13]), d[14]);
    float g = fminf(fminf(a, b), d[15]);
    float h = fminf(fminf(c, e), f);
    return fminf(g, h);
}

// Monotone float->uint encoding: preserves order for all finite floats.
__device__ __forceinline__ unsigned enc_f32(float x) {
    unsigned b = __float_as_uint(x);
    return (b & 0x80000000u) ? ~b : (b | 0x80000000u);
}
__device__ __forceinline__ float dec_f32(unsigned u) {
    unsigned b = (u & 0x80000000u) ? (u & 0x7FFFFFFFu) : ~u;
    return __uint_as_float(b);
}

// ---- Main: WPB=4 independent waves per 256-thread block (beats the
// workgroup-per-CU residency cap that single-wave blocks hit).
// grid = NWAVES/WPB = 2048 blocks -> 8 blocks/CU -> 32 waves/CU (8/SIMD).
__global__ __launch_bounds__(256, 8) void chamfer_main(
    const f16x8* __restrict__ TA, const f16x8* __restrict__ QF,
    unsigned* __restrict__ min8)
{
    const int wid  = blockIdx.x * WPB + (threadIdx.x >> 6);  // logical wave id
    const int lane = threadIdx.x & 63;
    const int qw   = wid & 63;
    const int bd   = (wid >> 6) & 7;     // dir*4+b (queries from cloud=dir)
    const int ms   = wid >> 9;           // 0..MSPLIT-1
    const int bdT  = bd ^ 4;             // db side = opposite cloud

    f16x8 qf[QB];
    size_t qbase = ((size_t)bd * TILES + qw * QB) * 64 + lane;
    #pragma unroll
    for (int t = 0; t < QB; ++t) qf[t] = QF[qbase + t * 64];

    const f32x16 zero = {0.f,0.f,0.f,0.f,0.f,0.f,0.f,0.f,
                         0.f,0.f,0.f,0.f,0.f,0.f,0.f,0.f};
    float mn[QB];
    #pragma unroll
    for (int t = 0; t < QB; ++t) mn[t] = 3.0e38f;

    const size_t tbase = ((size_t)bdT * TILES + ms * TPB) * 64 + lane;

    // Software-pipelined: prefetch next tile while reducing current.
    f16x8 a = TA[tbase];
    for (int i = 0; i < ITER - 1; ++i) {
        f16x8 n = TA[tbase + (size_t)(i + 1) * 64];
        #pragma unroll
        for (int t = 0; t < QB; ++t) {
            f32x16 d = __builtin_amdgcn_mfma_f32_32x32x16_f16(a, qf[t], zero, 0, 0, 0);
            mn[t] = fminf(mn[t], red16(d));
        }
        a = n;
    }
    #pragma unroll
    for (int t = 0; t < QB; ++t) {
        f32x16 d = __builtin_amdgcn_mfma_f32_32x32x16_f16(a, qf[t], zero, 0, 0, 0);
        mn[t] = fminf(mn[t], red16(d));
    }

    // Each lane covered 16 of 32 rows per tile; other 16 rows are in lane^32.
    #pragma unroll
    for (int t = 0; t < QB; ++t) mn[t] = fminf(mn[t], __shfl_xor(mn[t], 32));

    // Compact cross-ms combine: device-scope atomic umin on encoded floats
    // (fire-and-forget; 16 contenders per address spread over 64K addresses).
    if (lane < 32) {
        unsigned* basep = min8 + (size_t)bd * NPTS + qw * (QB * 32) + lane;
        #pragma unroll
        for (int t = 0; t < QB; ++t) atomicMin(basep + t * 32, enc_f32(mn[t]));
    }
}

// ---- Reduce: decode min, + |q|^2, sum, scale ----
__global__ __launch_bounds__(256) void chamfer_reduce(
    const unsigned* __restrict__ min8, const float* __restrict__ H,
    float* __restrict__ out)
{
    const int q = blockIdx.x * 256 + threadIdx.x;   // bd*8192 + n
    float acc = dec_f32(min8[q]) + H[q];
    #pragma unroll
    for (int off = 32; off > 0; off >>= 1) acc += __shfl_down(acc, off);

    __shared__ float sdata[4];
    if ((threadIdx.x & 63) == 0) sdata[threadIdx.x >> 6] = acc;
    __syncthreads();
    if (threadIdx.x == 0) {
        float t = (sdata[0] + sdata[1]) + (sdata[2] + sdata[3]);
        atomicAdd(out, t * (1.0f / (float)(BATCH * NPTS)));
    }
}

extern "C" void kernel_launch(void* const* d_in, const int* in_sizes, int n_in,
                              void* d_out, int out_size, void* d_ws, size_t ws_size,
                              hipStream_t stream) {
    const float* src = (const float*)d_in[0];   // (B, N, 3) fp32
    const float* tgt = (const float*)d_in[1];   // (B, M, 3) fp32
    float* out = (float*)d_out;

    f16x8*    TA   = (f16x8*)((char*)d_ws + TA_OFF);
    f16x8*    QF   = (f16x8*)((char*)d_ws + QF_OFF);
    float*    H    = (float*)((char*)d_ws + H_OFF);
    unsigned* MIN8 = (unsigned*)((char*)d_ws + MIN_OFF);

    chamfer_prepack<<<NQTOT / 256, 256, 0, stream>>>(src, tgt, TA, QF, H, MIN8, out);
    chamfer_main<<<NWAVES / WPB, 256, 0, stream>>>(TA, QF, MIN8);
    chamfer_reduce<<<NQTOT / 256, 256, 0, stream>>>(MIN8, H, out);
}